// Round 1
// baseline (813.760 us; speedup 1.0000x reference)
//
#include <hip/hip_runtime.h>
#include <hip/hip_bf16.h>

#define HID 512
#define NH  8
#define DD  64
#define GG  64
#define EPSF 1e-5f

typedef __attribute__((ext_vector_type(8))) short short8;
typedef __attribute__((ext_vector_type(4))) float floatx4;

__device__ __forceinline__ short f2bf(float f) {
    union { float f; unsigned u; } v; v.f = f;
    unsigned r = v.u + 0x7fffu + ((v.u >> 16) & 1u);
    return (short)(r >> 16);
}
__device__ __forceinline__ float bf2f(short s) {
    union { unsigned u; float f; } v;
    v.u = ((unsigned)(unsigned short)s) << 16;
    return v.f;
}

#define GLOAD_LDS16(g, l) __builtin_amdgcn_global_load_lds( \
    (const __attribute__((address_space(1))) unsigned int*)(g), \
    (__attribute__((address_space(3))) unsigned int*)(l), 16, 0, 0)

// ---------------------------------------------------------------------------
// cast x (f32) -> x_bf (bf16), 8 elems/thread
// ---------------------------------------------------------------------------
__global__ __launch_bounds__(256)
void cast_kernel(const float* __restrict__ x, short* __restrict__ xb, int n8) {
    int i = blockIdx.x * 256 + threadIdx.x;
    if (i >= n8) return;
    const float4* p = (const float4*)(x + (size_t)i * 8);
    float4 a = p[0], b = p[1];
    short8 v;
    v[0] = f2bf(a.x); v[1] = f2bf(a.y); v[2] = f2bf(a.z); v[3] = f2bf(a.w);
    v[4] = f2bf(b.x); v[5] = f2bf(b.y); v[6] = f2bf(b.z); v[7] = f2bf(b.w);
    *(short8*)(xb + (size_t)i * 8) = v;
}

// ---------------------------------------------------------------------------
// fold1: Wcat (1024x512 bf16) = [Wfx ; temp[h] * (Ws @ Wx_head)]
//        bias_cat (1024 f32)  = [bfx ; temp[h] * (Ws @ bx_head + bs)]
// ---------------------------------------------------------------------------
__global__ void fold1_kernel(const float* __restrict__ Wx, const float* __restrict__ bx,
                             const float* __restrict__ Wfx, const float* __restrict__ bfx,
                             const float* __restrict__ Ws, const float* __restrict__ bs,
                             const float* __restrict__ temp,
                             short* __restrict__ Wcat, float* __restrict__ bias_cat) {
    int idx = blockIdx.x * 256 + threadIdx.x;   // 0 .. 1024*512-1
    int row = idx >> 9;
    int k = idx & 511;
    float val;
    if (row < 512) {
        val = Wfx[row * 512 + k];
        if (k == 0) bias_cat[row] = bfx[row];
    } else {
        int hg = row - 512;
        int h = hg >> 6, g = hg & 63;
        float t = temp[h];
        float s = 0.f;
        #pragma unroll 8
        for (int d = 0; d < 64; ++d) s += Ws[g * 64 + d] * Wx[(h * 64 + d) * 512 + k];
        val = s * t;
        if (k == 0) {
            float b = 0.f;
            for (int d = 0; d < 64; ++d) b += Ws[g * 64 + d] * bx[h * 64 + d];
            bias_cat[row] = (b + bs[g]) * t;
        }
    }
    Wcat[idx] = f2bf(val);
}

// ---------------------------------------------------------------------------
// gemm256: C(M x ncols) = A(M x 512) @ B(ncols x 512)^T + bias, bf16 MFMA.
// 256x256 tile / BK=64 / 8 waves (2M x 4N) / 128 KiB LDS dbuf — the 8-phase
// counted-vmcnt schedule (T2+T3+T4+T5). K fixed at 512: 8 K-tiles, 4 iters.
//
// LDS layout: [buf][row][pchunk(8 x 16B)], pchunk = chunk ^ (row&7). Applied
// via pre-swizzled GLOBAL source addr (gload_lds dest stays linear) +
// swizzled ds_read addr. Frag reads then spread 64 lanes uniformly over all
// 8 chunk columns -> optimal 8 words/bank for ds_read_b128.
//
// Per K-tile (4 phases): B-frags (all 4j x 2ks) read at phase 0 and held in
// regs (B buffer dead after phase 0); phase p computes acc rows i={2p,2p+1}.
// Staging (2 gload_lds per phase, 64 rows each), q = global phase 0..7 of an
// iteration computing K-tiles (2u [buf0], 2u+1 [buf1]):
//   q0: K(2u+1) A L1,L3   q1: K(2u+2) B L0,L1   q2: K(2u+2) B L2,L3
//   q3: K(2u+2) A L0,L2   q4: K(2u+2) A L1,L3   q5: K(2u+3) B L0,L1
//   q6: K(2u+3) B L2,L3   q7: K(2u+3) A L0,L2
// Each dest region is dead (last read >= 1 closing barrier before issue).
// vmcnt(6) at end of q3/q7 (3 half-tiles in flight) guarantees the next
// K-tile fully landed; never drains to 0 in the main loop (T4).
// ---------------------------------------------------------------------------
template <bool OUT_F32, bool FUSE_SM>
__global__ __launch_bounds__(512, 2)
void gemm256(const short* __restrict__ A, int lda,
             const short* __restrict__ B,           // (ncols x 512) bf16 row-major
             const float* __restrict__ bias,
             void* __restrict__ Cp, int ldc,
             int M, int clog2, int Rtiles) {
    __shared__ short As[2][256 * 64];
    __shared__ short Bs[2][256 * 64];

    const int id = blockIdx.x;
    const int xcd = id & 7;
    const int s = id >> 3;
    const int cblk = s & ((1 << clog2) - 1);
    const int slice = (Rtiles + 7) >> 3;
    const int rt = xcd * slice + (s >> clog2);
    if (rt >= Rtiles) return;

    const int tid = threadIdx.x;
    const int wid = tid >> 6;
    const int lane = tid & 63;
    const int wm = wid >> 2, wn = wid & 3;          // 2 x 4 wave grid
    const int lr = lane & 15, lq = lane >> 4;
    const int row0 = rt * 256, col0 = cblk * 256;

    // staging: one gload_lds covers 64 rows; thread -> (srow, schunk) with
    // pre-swizzled source chunk so LDS[row][pch] = G[row][pch ^ (row&7)]
    const int srow = tid >> 3;                      // 0..63
    const int schunk = (tid & 7) ^ (srow & 7);
    const short* Asrc = A + (size_t)(row0 + srow) * lda + schunk * 8;
    const short* Bsrc = B + (size_t)(col0 + srow) * lda + schunk * 8;
    const int ldst = wid * 512;                     // wave-uniform dest (shorts)

#define SA(buf, kt, Lk) GLOAD_LDS16(Asrc + (size_t)((Lk) * 64) * lda + (kt) * 64, \
                                    &As[buf][(Lk) * 4096 + ldst])
#define SB(buf, kt, Lk) GLOAD_LDS16(Bsrc + (size_t)((Lk) * 64) * lda + (kt) * 64, \
                                    &Bs[buf][(Lk) * 4096 + ldst])

    // frag read offsets (row&7 == lr&7 for all frag rows since 16 ≡ 0 mod 8)
    const int axor = lr & 7;
    const int coff0 = (lq ^ axor) * 8;
    const int coff1 = ((4 + lq) ^ axor) * 8;
    const int aoff = (wm * 128 + lr) * 64;
    const int boff = (wn * 64 + lr) * 64;

    floatx4 acc[8][4];
    #pragma unroll
    for (int i = 0; i < 8; ++i)
        #pragma unroll
        for (int j = 0; j < 4; ++j) acc[i][j] = (floatx4)(0.f);

    // prologue: K0 complete (8 loads) + K1 all-but-A-L1L3 (6 loads)
    SA(0, 0, 0); SA(0, 0, 1); SA(0, 0, 2); SA(0, 0, 3);
    SB(0, 0, 0); SB(0, 0, 1); SB(0, 0, 2); SB(0, 0, 3);
    SB(1, 1, 0); SB(1, 1, 1); SB(1, 1, 2); SB(1, 1, 3);
    SA(1, 1, 0); SA(1, 1, 2);
    asm volatile("s_waitcnt vmcnt(6)" ::: "memory");   // K0 landed
    __builtin_amdgcn_s_barrier();

    short8 bfr[4][2];
    short8 af[2][2];

    #pragma unroll 1
    for (int u = 0; u < 4; ++u) {
        const int st = (u < 3);
        #pragma unroll
        for (int cb = 0; cb < 2; ++cb) {            // K-tile 2u+cb in buf cb
            #pragma unroll
            for (int p = 0; p < 4; ++p) {
                const int q = cb * 4 + p;
                // --- ds-loads for this phase ---
                if (p == 0) {
                    #pragma unroll
                    for (int j = 0; j < 4; ++j) {
                        bfr[j][0] = *(const short8*)&Bs[cb][boff + j * 1024 + coff0];
                        bfr[j][1] = *(const short8*)&Bs[cb][boff + j * 1024 + coff1];
                    }
                }
                #pragma unroll
                for (int i2 = 0; i2 < 2; ++i2) {
                    af[i2][0] = *(const short8*)&As[cb][aoff + (2 * p + i2) * 1024 + coff0];
                    af[i2][1] = *(const short8*)&As[cb][aoff + (2 * p + i2) * 1024 + coff1];
                }
                // --- stage one half-tile (2 gload_lds) ---
                if (q == 0)      { SA(1, 2 * u + 1, 1); SA(1, 2 * u + 1, 3); }
                else if (st) {
                    if (q == 1)      { SB(0, 2 * u + 2, 0); SB(0, 2 * u + 2, 1); }
                    else if (q == 2) { SB(0, 2 * u + 2, 2); SB(0, 2 * u + 2, 3); }
                    else if (q == 3) { SA(0, 2 * u + 2, 0); SA(0, 2 * u + 2, 2); }
                    else if (q == 4) { SA(0, 2 * u + 2, 1); SA(0, 2 * u + 2, 3); }
                    else if (q == 5) { SB(1, 2 * u + 3, 0); SB(1, 2 * u + 3, 1); }
                    else if (q == 6) { SB(1, 2 * u + 3, 2); SB(1, 2 * u + 3, 3); }
                    else             { SA(1, 2 * u + 3, 0); SA(1, 2 * u + 3, 2); }
                }
                // --- counted vmcnt once per K-tile (T4) ---
                if (q == 3) {
                    if (st) asm volatile("s_waitcnt vmcnt(6)" ::: "memory");
                    else    asm volatile("s_waitcnt vmcnt(0)" ::: "memory");
                } else if (q == 7 && st) {
                    asm volatile("s_waitcnt vmcnt(6)" ::: "memory");
                }
                __builtin_amdgcn_s_barrier();
                __builtin_amdgcn_s_setprio(1);
                #pragma unroll
                for (int ks = 0; ks < 2; ++ks)
                    #pragma unroll
                    for (int i2 = 0; i2 < 2; ++i2)
                        #pragma unroll
                        for (int j = 0; j < 4; ++j)
                            acc[2 * p + i2][j] = __builtin_amdgcn_mfma_f32_16x16x32_bf16(
                                af[i2][ks], bfr[j][ks], acc[2 * p + i2][j], 0, 0, 0);
                __builtin_amdgcn_s_setprio(0);
                __builtin_amdgcn_s_barrier();
            }
        }
    }
#undef SA
#undef SB

    // epilogue (bias load kept after loop: asm memory clobbers stop hoisting)
    float bcol[4];
    #pragma unroll
    for (int j = 0; j < 4; ++j) bcol[j] = bias[col0 + wn * 64 + j * 16 + lr];

    const bool do_sm = FUSE_SM && (col0 >= 512);
    #pragma unroll
    for (int i = 0; i < 8; ++i) {
        #pragma unroll
        for (int r = 0; r < 4; ++r) {
            const int grow = row0 + wm * 128 + i * 16 + lq * 4 + r;
            float v[4];
            #pragma unroll
            for (int j = 0; j < 4; ++j) v[j] = acc[i][j][r] + bcol[j];
            if (do_sm) {
                float m = fmaxf(fmaxf(v[0], v[1]), fmaxf(v[2], v[3]));
                #pragma unroll
                for (int off = 1; off < 16; off <<= 1) m = fmaxf(m, __shfl_xor(m, off));
                float sum = 0.f;
                #pragma unroll
                for (int j = 0; j < 4; ++j) { v[j] = __expf(v[j] - m); sum += v[j]; }
                #pragma unroll
                for (int off = 1; off < 16; off <<= 1) sum += __shfl_xor(sum, off);
                const float inv = 1.f / sum;
                #pragma unroll
                for (int j = 0; j < 4; ++j) v[j] *= inv;
            }
            if (grow < M) {
                #pragma unroll
                for (int j = 0; j < 4; ++j) {
                    const int gcol = col0 + wn * 64 + j * 16 + lr;
                    if constexpr (OUT_F32) ((float*)Cp)[(size_t)grow * ldc + gcol] = v[j];
                    else                   ((short*)Cp)[(size_t)grow * ldc + gcol] = f2bf(v[j]);
                }
            }
        }
    }
}

// ---------------------------------------------------------------------------
// pool_mfma: tok_raw[h,g,d] += sum_n w[n,h,g]*fx[n,h,d]; norm[h,g] += sum_n w
// (unchanged)
// ---------------------------------------------------------------------------
__global__ __launch_bounds__(256)
void pool_mfma(const short* __restrict__ mid, float* __restrict__ tok_raw,
               float* __restrict__ norm, int N, int chunk) {
    const int h = blockIdx.y;
    const int n0 = blockIdx.x * chunk;
    if (n0 >= N) return;
    const int ksteps = (min(chunk, N - n0)) >> 5;

    const int tid = threadIdx.x;
    const int wid = tid >> 6, lane = tid & 63;
    const int lr = lane & 15, lq = lane >> 4;
    const int wg = (wid >> 1) * 32, wd = (wid & 1) * 32;

    __shared__ short wt[32 * 72];
    __shared__ short ft[32 * 72];

    const int sn = tid >> 3;
    const int sc0 = (tid & 7) * 8;
    const int scr = (sc0 + 16 * ((sn >> 3) & 3)) & 63;
    const int st_off = sn * 72 + scr;

    const int ra = ((wg + lr) + 16 * lq) & 63;
    const int rb = ((wd + lr) + 16 * lq) & 63;

    const short* wbase = mid + (size_t)n0 * 1024 + 512 + h * 64;
    const short* fbase = mid + (size_t)n0 * 1024 + h * 64;

    floatx4 acc[2][2];
    #pragma unroll
    for (int i = 0; i < 2; ++i)
        #pragma unroll
        for (int j = 0; j < 2; ++j) acc[i][j] = (floatx4)(0.f);
    floatx4 accn[2];
    accn[0] = (floatx4)(0.f); accn[1] = (floatx4)(0.f);

    short8 ones;
    #pragma unroll
    for (int j = 0; j < 8; ++j) ones[j] = (short)0x3F80;

    for (int ks = 0; ks < ksteps; ++ks) {
        const size_t roff = (size_t)(ks * 32 + sn) * 1024;
        short8 wv = *(const short8*)(wbase + roff + sc0);
        short8 fv = *(const short8*)(fbase + roff + sc0);
        __syncthreads();
        *(short8*)&wt[st_off] = wv;
        *(short8*)&ft[st_off] = fv;
        __syncthreads();

        short8 af[2], bf_[2];
        #pragma unroll
        for (int i = 0; i < 2; ++i) {
            short tmpv[8];
            #pragma unroll
            for (int j = 0; j < 8; ++j)
                tmpv[j] = wt[(lq * 8 + j) * 72 + ((ra + i * 16) & 63)];
            af[i] = *(const short8*)tmpv;
        }
        #pragma unroll
        for (int j2 = 0; j2 < 2; ++j2) {
            short tmpv[8];
            #pragma unroll
            for (int j = 0; j < 8; ++j)
                tmpv[j] = ft[(lq * 8 + j) * 72 + ((rb + j2 * 16) & 63)];
            bf_[j2] = *(const short8*)tmpv;
        }
        #pragma unroll
        for (int i = 0; i < 2; ++i)
            #pragma unroll
            for (int j = 0; j < 2; ++j)
                acc[i][j] = __builtin_amdgcn_mfma_f32_16x16x32_bf16(af[i], bf_[j], acc[i][j], 0, 0, 0);
        if (wd == 0) {
            #pragma unroll
            for (int i = 0; i < 2; ++i)
                accn[i] = __builtin_amdgcn_mfma_f32_16x16x32_bf16(af[i], ones, accn[i], 0, 0, 0);
        }
    }

    #pragma unroll
    for (int i = 0; i < 2; ++i) {
        #pragma unroll
        for (int r = 0; r < 4; ++r) {
            int g = wg + i * 16 + lq * 4 + r;
            #pragma unroll
            for (int j = 0; j < 2; ++j) {
                int d = wd + j * 16 + lr;
                atomicAdd(&tok_raw[(h * 64 + g) * 64 + d], acc[i][j][r]);
            }
        }
    }
    if (wd == 0 && lr == 0) {
        #pragma unroll
        for (int i = 0; i < 2; ++i)
            #pragma unroll
            for (int r = 0; r < 4; ++r)
                atomicAdd(&norm[h * 64 + wg + i * 16 + lq * 4 + r], accn[i][r]);
    }
}

// ---------------------------------------------------------------------------
// attn: per head, G=64 tokens (unchanged)
// ---------------------------------------------------------------------------
__global__ __launch_bounds__(256)
void attn_kernel(const float* __restrict__ tok_raw, const float* __restrict__ norm,
                 const float* __restrict__ Wq, const float* __restrict__ Wk,
                 const float* __restrict__ Wv, const float* __restrict__ Wo,
                 float* __restrict__ out_tok) {
    const int h = blockIdx.x;
    const int tid = threadIdx.x;
    const int g = tid & 63, part = tid >> 6;
    const int o0 = part * 16;

    __shared__ float tk[64][65];
    __shared__ float qq[64][65];
    __shared__ float kk[64][65];
    __shared__ float vv[64][65];
    __shared__ float pp[64][65];
    __shared__ float od[64][65];

    const float inv = 1.f / (norm[h * 64 + g] + EPSF);
    #pragma unroll
    for (int dd = 0; dd < 16; ++dd) {
        int d = o0 + dd;
        tk[g][d] = tok_raw[(size_t)(h * 64 + g) * 64 + d] * inv;
    }
    __syncthreads();

    float t[64];
    #pragma unroll
    for (int d = 0; d < 64; ++d) t[d] = tk[g][d];
    #pragma unroll
    for (int oo = 0; oo < 16; ++oo) {
        int o = o0 + oo;
        float sq = 0.f, sk = 0.f, sv = 0.f;
        #pragma unroll
        for (int d = 0; d < 64; ++d) {
            float td = t[d];
            sq += td * Wq[o * 64 + d];
            sk += td * Wk[o * 64 + d];
            sv += td * Wv[o * 64 + d];
        }
        qq[g][o] = sq; kk[g][o] = sk; vv[g][o] = sv;
    }
    __syncthreads();

    float q[64];
    #pragma unroll
    for (int o = 0; o < 64; ++o) q[o] = qq[g][o];
    #pragma unroll
    for (int jj = 0; jj < 16; ++jj) {
        int j = o0 + jj;
        float s = 0.f;
        #pragma unroll
        for (int o = 0; o < 64; ++o) s += q[o] * kk[j][o];
        pp[g][j] = s * 0.125f;
    }
    __syncthreads();

    float sr[64];
    float mx = -1e30f;
    #pragma unroll
    for (int j = 0; j < 64; ++j) { sr[j] = pp[g][j]; mx = fmaxf(mx, sr[j]); }
    float sum = 0.f;
    #pragma unroll
    for (int j = 0; j < 64; ++j) { sr[j] = __expf(sr[j] - mx); sum += sr[j]; }
    const float isum = 1.f / sum;

    #pragma unroll
    for (int dd = 0; dd < 16; ++dd) {
        int d = o0 + dd;
        float a = 0.f;
        #pragma unroll
        for (int j = 0; j < 64; ++j) a += sr[j] * vv[j][d];
        od[g][d] = a * isum;
    }
    __syncthreads();

    float ot[64];
    #pragma unroll
    for (int d = 0; d < 64; ++d) ot[d] = od[g][d];
    #pragma unroll
    for (int oo = 0; oo < 16; ++oo) {
        int o = o0 + oo;
        float a = 0.f;
        #pragma unroll
        for (int d = 0; d < 64; ++d) a += ot[d] * Wo[o * 64 + d];
        out_tok[(size_t)(h * 64 + g) * 64 + o] = a;
    }
}

// ---------------------------------------------------------------------------
// fold2: V[o, h*64+g] = sum_d out_tok[h,g,d] * Wout[o, h*64+d]  (bf16 out)
// ---------------------------------------------------------------------------
__global__ void fold2_kernel(const float* __restrict__ out_tok,
                             const float* __restrict__ Wout, short* __restrict__ Vbf) {
    int idx = blockIdx.x * 256 + threadIdx.x;
    int o = idx >> 9, hg = idx & 511;
    int h = hg >> 6;
    const float* ot = out_tok + (size_t)hg * 64;
    const float* wo = Wout + (size_t)o * 512 + h * 64;
    float s = 0.f;
    #pragma unroll 8
    for (int d = 0; d < 64; ++d) s += ot[d] * wo[d];
    Vbf[idx] = f2bf(s);
}

// ---------------------------------------------------------------------------
extern "C" void kernel_launch(void* const* d_in, const int* in_sizes, int n_in,
                              void* d_out, int out_size, void* d_ws, size_t ws_size,
                              hipStream_t stream) {
    const float* x    = (const float*)d_in[0];
    const float* Wx   = (const float*)d_in[1];
    const float* bx   = (const float*)d_in[2];
    const float* Wfx  = (const float*)d_in[3];
    const float* bfx  = (const float*)d_in[4];
    const float* Ws   = (const float*)d_in[5];
    const float* bs   = (const float*)d_in[6];
    const float* temp = (const float*)d_in[7];
    const float* Wq   = (const float*)d_in[8];
    const float* Wk   = (const float*)d_in[9];
    const float* Wv   = (const float*)d_in[10];
    const float* Wo   = (const float*)d_in[11];
    const float* Wout = (const float*)d_in[12];
    const float* bout = (const float*)d_in[13];

    const int N = in_sizes[0] / HID;

    char* p = (char*)d_ws;
    short* mid = (short*)p;           p += (size_t)N * 1024 * 2;       // fx | w (bf16)
    short* Wcat = (short*)p;          p += (size_t)1024 * 512 * 2;
    float* bias_cat = (float*)p;      p += 1024 * 4;
    float* tok_raw = (float*)p;       p += (size_t)NH * GG * DD * 4;   // contiguous with norm
    float* norm_ = (float*)p;         p += (size_t)NH * GG * 4;
    float* out_tok = (float*)p;       p += (size_t)NH * GG * DD * 4;
    short* Vbf = (short*)p;           p += (size_t)512 * 512 * 2;
    short* x_bf = (short*)d_out;     // d_out (N*512 f32) hosts x_bf until GEMM2

    cast_kernel<<<(N * 512 / 8 + 255) / 256, 256, 0, stream>>>(x, x_bf, N * 512 / 8);
    fold1_kernel<<<2048, 256, 0, stream>>>(Wx, bx, Wfx, bfx, Ws, bs, temp, Wcat, bias_cat);

    const int R = (N + 255) / 256;
    const int slice = (R + 7) / 8;

    // GEMM1: 4 col tiles of 256, fused softmax on logits half
    gemm256<false, true><<<8 * slice * 4, 512, 0, stream>>>(
        x_bf, HID, Wcat, bias_cat, (void*)mid, 1024, N, 2, R);

    hipMemsetAsync(tok_raw, 0, (size_t)(NH * GG * DD + NH * GG) * 4, stream);

    // pool: split-K MFMA; chunk multiple of 32 (N=100000 is a multiple of 32)
    const int chunk = 544;                       // 17 k-steps per block
    dim3 g2((N + chunk - 1) / chunk, 8);
    pool_mfma<<<g2, 256, 0, stream>>>(mid, tok_raw, norm_, N, chunk);

    attn_kernel<<<8, 256, 0, stream>>>(tok_raw, norm_, Wq, Wk, Wv, Wo, out_tok);

    fold2_kernel<<<1024, 256, 0, stream>>>(out_tok, Wout, Vbf);

    // GEMM2: 2 col tiles of 256 (A = w half of mid, bf16; output f32 + bout)
    gemm256<true, false><<<8 * slice * 2, 512, 0, stream>>>(
        mid + 512, 1024, Vbf, bout, d_out, HID, N, 1, R);
}